// Round 8
// baseline (115.816 us; speedup 1.0000x reference)
//
#include <hip/hip_runtime.h>
#include <hip/hip_bf16.h>
#include <math.h>

#define NH 16
#define QL 2048
#define SL 2048
#define DD 64
#define BQ 128
#define PSTR 72
#define QK_SCALE_LOG2E 0.1803368801111f   // (8/64) * log2(e): fold softmax scale + ln2 into Q

typedef __attribute__((ext_vector_type(8))) short short8;
typedef __attribute__((ext_vector_type(4))) float floatx4;
typedef __attribute__((ext_vector_type(4))) unsigned short ushort4v;
typedef __attribute__((ext_vector_type(8))) unsigned short ushort8v;

__device__ __forceinline__ unsigned short f2bf(float x) {   // RNE fp32->bf16
    unsigned u = __float_as_uint(x);
    u += 0x7FFFu + ((u >> 16) & 1u);
    return (unsigned short)(u >> 16);
}
__device__ __forceinline__ unsigned int f2bf2u(float x, float y) {  // packed pair (low=x)
    __hip_bfloat162 h = __float22bfloat162_rn(make_float2(x, y));
    return *(unsigned int*)&h;
}
__device__ __forceinline__ float bf2f(unsigned short h) {
    return __uint_as_float((unsigned)h << 16);
}

// async global->LDS, 16B per lane; LDS dest = wave-uniform base + lane*16
__device__ __forceinline__ void gld16(const unsigned short* g, unsigned short* l) {
    __builtin_amdgcn_global_load_lds(
        (const __attribute__((address_space(1))) unsigned int*)g,
        (__attribute__((address_space(3))) unsigned int*)l, 16, 0, 0);
}

// ---------------- prep: K->bf16 + V->V^T bf16, one 512x512 launch (unchanged) ----------------
__global__ __launch_bounds__(512) void k_prep(
    const float* __restrict__ Kf, const float* __restrict__ Vf,
    unsigned short* __restrict__ Kb, unsigned short* __restrict__ Vtb)
{
    __shared__ unsigned short sT[64][PSTR];    // 9 KB: V-transpose scratch
    const int bx = (int)blockIdx.x, tid = (int)threadIdx.x;

    // K convert: NH*SL*DD/4 = 524288 float4 groups, 2 per thread
    const int gidx = bx * 512 + tid;
    #pragma unroll
    for (int k = 0; k < 2; ++k) {
        int idx = gidx + k * (512 * 512);
        float4 v = ((const float4*)Kf)[idx];
        ushort4v h = { f2bf(v.x), f2bf(v.y), f2bf(v.z), f2bf(v.w) };
        *(ushort4v*)(Kb + (size_t)idx * 4) = h;
    }

    // V transpose: block bx owns s-tile bx (16 heads x 32 tiles = 512)
    const int n = bx >> 5, s0 = (bx & 31) * 64;
    const float* vb = Vf + ((size_t)n * SL + s0) * DD;
    #pragma unroll
    for (int i = 0; i < 2; ++i) {
        int idx = tid + i * 512;
        int r = idx >> 4, c = (idx & 15) << 2;
        float4 v = *(const float4*)(vb + r * DD + c);
        sT[c + 0][r] = f2bf(v.x);
        sT[c + 1][r] = f2bf(v.y);
        sT[c + 2][r] = f2bf(v.z);
        sT[c + 3][r] = f2bf(v.w);
    }
    __syncthreads();
    const int d = tid >> 3, sg = tid & 7;
    unsigned short* out = Vtb + (size_t)n * DD * SL + (size_t)d * SL + s0 + sg * 8;
    ushort8v a;
    #pragma unroll
    for (int i = 0; i < 8; ++i) a[i] = sT[d][sg * 8 + i];
    *(ushort8v*)out = a;
}

// ---------------- attention: 8 waves as 2(s)x4(q) grid of 32q x 32s wave-tiles ----------------
// Wave (ws,wq) computes partial O for q in [q0+wq*32, +32) using s-half ws of each 64-tile.
// K/V LDS frags are read ONCE per wave and feed TWO q-fragments -> per-CU LDS reads
// drop from 147KB to 80KB per tile (the measured t_tile bottleneck, R7 counters).
// End: ws=1 publishes bf16 partials + row-sums via LDS; ws=0 merges, normalizes, stores fp32 O.
__global__ __launch_bounds__(512, 4) void k_attn(
    const float* __restrict__ Qf, const unsigned short* __restrict__ Kb,
    const unsigned short* __restrict__ Vtb, const int* __restrict__ plen_g,
    float* __restrict__ Og)
{
    // K/V: 64x64 bf16 tiles, row = 64 ushorts (128B, NO pad: global_load_lds needs lane*16 dest),
    // chunk c of row r at slot c ^ (r&7) (swizzle on the global fetch side).
    __shared__ unsigned short sK[3][64 * 64];    // 24 KB: triple-buffered, prefetch distance 2
    __shared__ unsigned short sVt[3][64 * 64];   // 24 KB
    __shared__ unsigned short sP[8 * 32 * 32];   // 16 KB: per-wave P[32q][32s] (also end merge buf)
    __shared__ float lsh[2][128];                // 1 KB: per-s-half row softmax denominators

    const int bx   = (int)blockIdx.x;
    const int n    = bx & (NH - 1);            // XCD = n % 8: per-head K/V L2 locality
    const int qt   = bx >> 4;
    const int q0   = qt * BQ;
    const int plen = plen_g[n];

    const int tid  = (int)threadIdx.x;
    const int wave = tid >> 6, lane = tid & 63, quad = lane >> 4, l16 = lane & 15;
    const int ws   = wave & 1;                 // s-half 0/1 within the 64-tile
    const int wq   = wave >> 1;                // q-quarter 0..3

    const int ptiles = (plen + 63) >> 6;       // 0..32 prefix tiles (last may be partial)
    const int d0     = q0 >> 6;                // even; diag tiles d0, d0+1
    const int e0     = (d0 >= ptiles) ? 1 : 0;
    const int e1     = (d0 + 1 >= ptiles) ? 1 : 0;
    const int total  = ptiles + e0 + e1;       // >= 2 always

    const int qgA = q0 + wq * 32 + l16;        // q-frag A global row
    const int qgB = qgA + 16;                  // q-frag B global row
    const int pm2 = (l16 & 3) * 8;             // sP XOR swizzle within 32-short rows (bits 3-4)

    const unsigned short* kh = Kb  + (size_t)n * SL * DD;
    const unsigned short* vh = Vtb + (size_t)n * DD * SL;

    // staging lane mapping: each of 8 waves moves one 1KB segment of K and of V per tile
    const int srow = wave * 8 + (lane >> 3);
    const int scol = ((lane & 7) ^ (srow & 7)) * 8;

    auto tile_of = [&](int i) -> int {
        if (i < ptiles) return i;
        if (i == ptiles) return e0 ? d0 : d0 + 1;
        return d0 + 1;
    };
    auto stage = [&](int t, int b) {           // exactly 2 global_load_lds per wave, uniform
        const unsigned short* kg = kh + ((size_t)t << 6) * DD;
        const unsigned short* vg = vh + (t << 6);
        gld16(kg + srow * DD + scol, sK[b] + wave * 512);
        gld16(vg + (size_t)srow * SL + scol, sVt[b] + wave * 512);
    };

    // Q fragments (4: two 16-row q-frags x two 32-d halves), scale folded in
    short8 bQ0A, bQ1A, bQ0B, bQ1B;
    {
        const float S = QK_SCALE_LOG2E;
        const float* qa = Qf + ((size_t)(n * QL + qgA)) * DD + quad * 8;
        const float* qb = Qf + ((size_t)(n * QL + qgB)) * DD + quad * 8;
        float4 a0 = *(const float4*)(qa);       float4 a1 = *(const float4*)(qa + 4);
        float4 a2 = *(const float4*)(qa + 32);  float4 a3 = *(const float4*)(qa + 36);
        float4 b0 = *(const float4*)(qb);       float4 b1 = *(const float4*)(qb + 4);
        float4 b2 = *(const float4*)(qb + 32);  float4 b3 = *(const float4*)(qb + 36);
        unsigned int uA0[4] = { f2bf2u(a0.x*S,a0.y*S), f2bf2u(a0.z*S,a0.w*S),
                                f2bf2u(a1.x*S,a1.y*S), f2bf2u(a1.z*S,a1.w*S) };
        unsigned int uA1[4] = { f2bf2u(a2.x*S,a2.y*S), f2bf2u(a2.z*S,a2.w*S),
                                f2bf2u(a3.x*S,a3.y*S), f2bf2u(a3.z*S,a3.w*S) };
        unsigned int uB0[4] = { f2bf2u(b0.x*S,b0.y*S), f2bf2u(b0.z*S,b0.w*S),
                                f2bf2u(b1.x*S,b1.y*S), f2bf2u(b1.z*S,b1.w*S) };
        unsigned int uB1[4] = { f2bf2u(b2.x*S,b2.y*S), f2bf2u(b2.z*S,b2.w*S),
                                f2bf2u(b3.x*S,b3.y*S), f2bf2u(b3.z*S,b3.w*S) };
        bQ0A = *(short8*)uA0;  bQ1A = *(short8*)uA1;
        bQ0B = *(short8*)uB0;  bQ1B = *(short8*)uB1;
    }

    // ---- prologue: stage tiles 0 and 1 (distance-2 pipeline fill) ----
    stage(tile_of(0), 0);
    if (total > 1) stage(tile_of(1), 1);

    floatx4 accA[4], accB[4];
    #pragma unroll
    for (int dt = 0; dt < 4; ++dt) {
        accA[dt] = (floatx4){0.f, 0.f, 0.f, 0.f};
        accB[dt] = (floatx4){0.f, 0.f, 0.f, 0.f};
    }
    float lsumA = 0.f, lsumB = 0.f;            // per-lane l partials (this wave's s-set only)
    unsigned short* pwA = sP + (wave * 32 + l16) * 32;   // P row qA (32 shorts/row)
    unsigned short* pwB = pwA + 16 * 32;                 // P row qB

    int bi = 0, bs = 2;
    for (int i = 0; i < total; ++i) {
        if (i + 2 <= total) {
            asm volatile("s_waitcnt vmcnt(2) lgkmcnt(0)" ::: "memory");
        } else {
            asm volatile("s_waitcnt vmcnt(0) lgkmcnt(0)" ::: "memory");
        }
        __builtin_amdgcn_s_barrier();          // all waves' iter-i loads now landed

        if (i + 2 < total) stage(tile_of(i + 2), bs);   // block-uniform condition

        const unsigned short* sk = sK[bi];
        const unsigned short* sv = sVt[bi];
        const int t  = tile_of(i);
        const int s0 = t << 6;

        // ---- S^T = K·Q^T for both q-frags: each aK frag loaded ONCE, used twice ----
        floatx4 sfA[2], sfB[2];
        #pragma unroll
        for (int st2 = 0; st2 < 2; ++st2) {
            sfA[st2] = (floatx4){0.f, 0.f, 0.f, 0.f};
            sfB[st2] = (floatx4){0.f, 0.f, 0.f, 0.f};
        }
        __builtin_amdgcn_s_setprio(1);
        #pragma unroll
        for (int st2 = 0; st2 < 2; ++st2) {
            int krow = ws * 32 + st2 * 16 + l16;
            short8 aK0 = *(const short8*)(sk + krow * 64 + (((0 * 4 + quad) ^ (krow & 7)) * 8));
            short8 aK1 = *(const short8*)(sk + krow * 64 + (((1 * 4 + quad) ^ (krow & 7)) * 8));
            sfA[st2] = __builtin_amdgcn_mfma_f32_16x16x32_bf16(aK0, bQ0A, sfA[st2], 0, 0, 0);
            sfA[st2] = __builtin_amdgcn_mfma_f32_16x16x32_bf16(aK1, bQ1A, sfA[st2], 0, 0, 0);
            sfB[st2] = __builtin_amdgcn_mfma_f32_16x16x32_bf16(aK0, bQ0B, sfB[st2], 0, 0, 0);
            sfB[st2] = __builtin_amdgcn_mfma_f32_16x16x32_bf16(aK1, bQ1B, sfB[st2], 0, 0, 0);
        }
        __builtin_amdgcn_s_setprio(0);

        // ---- fixed-max softmax: p = exp2(prescaled score); s = s0 + ws*32 + st2*16 + quad*4 + r ----
        if (s0 + 64 <= plen) {                 // fully-valid tile
            #pragma unroll
            for (int st2 = 0; st2 < 2; ++st2) {
                float a0 = __builtin_amdgcn_exp2f(sfA[st2][0]);
                float a1 = __builtin_amdgcn_exp2f(sfA[st2][1]);
                float a2 = __builtin_amdgcn_exp2f(sfA[st2][2]);
                float a3 = __builtin_amdgcn_exp2f(sfA[st2][3]);
                lsumA += (a0 + a1) + (a2 + a3);
                uint2 pkA = { f2bf2u(a0, a1), f2bf2u(a2, a3) };
                *(uint2*)(pwA + ((st2 * 16 + quad * 4) ^ pm2)) = pkA;
                float b0 = __builtin_amdgcn_exp2f(sfB[st2][0]);
                float b1 = __builtin_amdgcn_exp2f(sfB[st2][1]);
                float b2 = __builtin_amdgcn_exp2f(sfB[st2][2]);
                float b3 = __builtin_amdgcn_exp2f(sfB[st2][3]);
                lsumB += (b0 + b1) + (b2 + b3);
                uint2 pkB = { f2bf2u(b0, b1), f2bf2u(b2, b3) };
                *(uint2*)(pwB + ((st2 * 16 + quad * 4) ^ pm2)) = pkB;
            }
        } else {                               // partial/diag tile
            #pragma unroll
            for (int st2 = 0; st2 < 2; ++st2) {
                float pa[4], pb[4];
                #pragma unroll
                for (int r2 = 0; r2 < 4; ++r2) {
                    int s = s0 + ws * 32 + st2 * 16 + quad * 4 + r2;
                    bool va = (s < plen) || (s == qgA);
                    bool vb = (s < plen) || (s == qgB);
                    pa[r2] = __builtin_amdgcn_exp2f(va ? sfA[st2][r2] : -INFINITY);
                    pb[r2] = __builtin_amdgcn_exp2f(vb ? sfB[st2][r2] : -INFINITY);
                    lsumA += pa[r2];
                    lsumB += pb[r2];
                }
                uint2 pkA = { f2bf2u(pa[0], pa[1]), f2bf2u(pa[2], pa[3]) };
                uint2 pkB = { f2bf2u(pb[0], pb[1]), f2bf2u(pb[2], pb[3]) };
                *(uint2*)(pwA + ((st2 * 16 + quad * 4) ^ pm2)) = pkA;
                *(uint2*)(pwB + ((st2 * 16 + quad * 4) ^ pm2)) = pkB;
            }
        }

        // ---- PV (k=32 over this wave's s-half): each bV frag loaded ONCE, used twice ----
        __builtin_amdgcn_s_setprio(1);
        {
            short8 aPA = *(const short8*)(pwA + ((quad * 8) ^ pm2));
            short8 aPB = *(const short8*)(pwB + ((quad * 8) ^ pm2));
            #pragma unroll
            for (int dt = 0; dt < 4; ++dt) {
                int vrow = dt * 16 + l16;
                short8 bV = *(const short8*)(sv + vrow * 64 + (((ws * 4 + quad) ^ (vrow & 7)) * 8));
                accA[dt] = __builtin_amdgcn_mfma_f32_16x16x32_bf16(aPA, bV, accA[dt], 0, 0, 0);
                accB[dt] = __builtin_amdgcn_mfma_f32_16x16x32_bf16(aPB, bV, accB[dt], 0, 0, 0);
            }
        }
        __builtin_amdgcn_s_setprio(0);

        bi = (bi == 2) ? 0 : bi + 1;
        bs = (bs == 2) ? 0 : bs + 1;
    }

    // ---- epilogue: merge the ws-pair, normalize, store fp32 O ----
    lsumA += __shfl_xor(lsumA, 16, 64);
    lsumA += __shfl_xor(lsumA, 32, 64);        // sum over quads -> full partial for this s-half
    lsumB += __shfl_xor(lsumB, 16, 64);
    lsumB += __shfl_xor(lsumB, 32, 64);
    if (quad == 0) {
        lsh[ws][wq * 32 + l16]      = lsumA;
        lsh[ws][wq * 32 + 16 + l16] = lsumB;
    }
    __syncthreads();                           // all PV reads of sP done; sP reusable as merge buf

    unsigned short* mrg = sP;                  // [128 q][64 d] bf16 = 16 KB
    if (ws == 1) {                             // publish bf16 partials (same numerics as R3 merge)
        #pragma unroll
        for (int dt = 0; dt < 4; ++dt) {
            #pragma unroll
            for (int r2 = 0; r2 < 4; ++r2) {
                mrg[(wq * 32 + quad * 4 + r2) * 64 + dt * 16 + l16]      = f2bf(accA[dt][r2]);
                mrg[(wq * 32 + 16 + quad * 4 + r2) * 64 + dt * 16 + l16] = f2bf(accB[dt][r2]);
            }
        }
    }
    __syncthreads();

    if (ws == 0) {
        float invA[4], invB[4];
        #pragma unroll
        for (int r2 = 0; r2 < 4; ++r2) {
            int qa = wq * 32 + quad * 4 + r2;
            invA[r2] = 1.0f / (lsh[0][qa] + lsh[1][qa]);           // > 0: diag always unmasked
            invB[r2] = 1.0f / (lsh[0][qa + 16] + lsh[1][qa + 16]);
        }
        float* ob = Og + ((size_t)n * QL + q0 + wq * 32) * DD + l16;
        #pragma unroll
        for (int r2 = 0; r2 < 4; ++r2) {
            float* orA = ob + (quad * 4 + r2) * DD;
            float* orB = ob + (16 + quad * 4 + r2) * DD;
            #pragma unroll
            for (int dt = 0; dt < 4; ++dt) {
                float pA = bf2f(mrg[(wq * 32 + quad * 4 + r2) * 64 + dt * 16 + l16]);
                float pB = bf2f(mrg[(wq * 32 + 16 + quad * 4 + r2) * 64 + dt * 16 + l16]);
                orA[dt * 16] = (accA[dt][r2] + pA) * invA[r2];
                orB[dt * 16] = (accB[dt][r2] + pB) * invB[r2];
            }
        }
    }
}

extern "C" void kernel_launch(void* const* d_in, const int* in_sizes, int n_in,
                              void* d_out, int out_size, void* d_ws, size_t ws_size,
                              hipStream_t stream) {
    const float* Qf   = (const float*)d_in[0];
    const float* Kf   = (const float*)d_in[1];
    const float* Vf   = (const float*)d_in[2];
    const int*   plen = (const int*)d_in[3];
    float* Og = (float*)d_out;

    char* ws = (char*)d_ws;
    unsigned short* Kb  = (unsigned short*)(ws);                 // 4 MB
    unsigned short* Vtb = (unsigned short*)(ws + (4u << 20));    // 4 MB

    k_prep<<<512, 512, 0, stream>>>(Kf, Vf, Kb, Vtb);
    k_attn<<<NH * (QL / BQ), 512, 0, stream>>>(Qf, Kb, Vtb, plen, Og);
}

// Round 9
// 103.265 us; speedup vs baseline: 1.1215x; 1.1215x over previous
//
#include <hip/hip_runtime.h>
#include <hip/hip_bf16.h>
#include <math.h>

#define NH 16
#define QL 2048
#define SL 2048
#define DD 64
#define BQ 128
#define NSPLIT 2
#define PSTR 72
#define QK_SCALE_LOG2E 0.1803368801111f   // (8/64) * log2(e): fold softmax scale + ln2 into Q

typedef __attribute__((ext_vector_type(8))) short short8;
typedef __attribute__((ext_vector_type(4))) float floatx4;
typedef __attribute__((ext_vector_type(4))) unsigned short ushort4v;
typedef __attribute__((ext_vector_type(8))) unsigned short ushort8v;

__device__ __forceinline__ unsigned short f2bf(float x) {   // RNE fp32->bf16
    unsigned u = __float_as_uint(x);
    u += 0x7FFFu + ((u >> 16) & 1u);
    return (unsigned short)(u >> 16);
}
__device__ __forceinline__ unsigned int f2bf2u(float x, float y) {  // packed pair (low=x)
    __hip_bfloat162 h = __float22bfloat162_rn(make_float2(x, y));
    return *(unsigned int*)&h;
}
__device__ __forceinline__ float bf2f(unsigned short h) {
    return __uint_as_float((unsigned)h << 16);
}

// async global->LDS, 16B per lane; LDS dest = wave-uniform base + lane*16
__device__ __forceinline__ void gld16(const unsigned short* g, unsigned short* l) {
    __builtin_amdgcn_global_load_lds(
        (const __attribute__((address_space(1))) unsigned int*)g,
        (__attribute__((address_space(3))) unsigned int*)l, 16, 0, 0);
}

// ---------------- prep: K->bf16 + V->V^T bf16, one 512x512 launch (R3 verbatim) ----------------
__global__ __launch_bounds__(512) void k_prep(
    const float* __restrict__ Kf, const float* __restrict__ Vf,
    unsigned short* __restrict__ Kb, unsigned short* __restrict__ Vtb)
{
    __shared__ unsigned short sT[64][PSTR];    // 9 KB: V-transpose scratch
    const int bx = (int)blockIdx.x, tid = (int)threadIdx.x;

    // K convert: NH*SL*DD/4 = 524288 float4 groups, 2 per thread
    const int gidx = bx * 512 + tid;
    #pragma unroll
    for (int k = 0; k < 2; ++k) {
        int idx = gidx + k * (512 * 512);
        float4 v = ((const float4*)Kf)[idx];
        ushort4v h = { f2bf(v.x), f2bf(v.y), f2bf(v.z), f2bf(v.w) };
        *(ushort4v*)(Kb + (size_t)idx * 4) = h;
    }

    // V transpose: block bx owns s-tile bx (16 heads x 32 tiles = 512)
    const int n = bx >> 5, s0 = (bx & 31) * 64;
    const float* vb = Vf + ((size_t)n * SL + s0) * DD;
    #pragma unroll
    for (int i = 0; i < 2; ++i) {
        int idx = tid + i * 512;
        int r = idx >> 4, c = (idx & 15) << 2;
        float4 v = *(const float4*)(vb + r * DD + c);
        sT[c + 0][r] = f2bf(v.x);
        sT[c + 1][r] = f2bf(v.y);
        sT[c + 2][r] = f2bf(v.z);
        sT[c + 3][r] = f2bf(v.w);
    }
    __syncthreads();
    const int d = tid >> 3, sg = tid & 7;
    unsigned short* out = Vtb + (size_t)n * DD * SL + (size_t)d * SL + s0 + sg * 8;
    ushort8v a;
    #pragma unroll
    for (int i = 0; i < 8; ++i) a[i] = sT[d][sg * 8 + i];
    *(ushort8v*)out = a;
}

// ---------------- attention: R3 structure, TWO tiles per barrier segment (pair pipeline) ----------------
// Split sp owns s-tiles with (tile & 1) == sp; diag tile d0+sp has parity sp -> every block >= 1 tile.
// 4 LDS tile-buffers = pair-level double buffer. Per segment: drain+barrier, stage next pair,
// compute tile 2p then 2p+1 (independent chains -> compiler overlaps QK(2p+1) under SM/PV(2p)).
// Halves barrier+drain events vs R3; attacks the measured latency-bound regime (R7/R8 counters).
__global__ __launch_bounds__(512, 4) void k_attn(
    const float* __restrict__ Qf, const unsigned short* __restrict__ Kb,
    const unsigned short* __restrict__ Vtb, const int* __restrict__ plen_g,
    unsigned short* __restrict__ Opb, float* __restrict__ Lp)
{
    // K/V: 64x64 bf16 tiles, row = 64 ushorts (128B, NO pad: global_load_lds needs lane*16 dest),
    // chunk c of row r at slot c ^ (r&7) (swizzle on the global fetch side).
    __shared__ unsigned short sK[4][64 * 64];    // 32 KB: 2 pairs x 2 tiles
    __shared__ unsigned short sVt[4][64 * 64];   // 32 KB
    __shared__ unsigned short sP[8 * 16 * 64];   // 16 KB (wave-private rows)
    // total 80 KB -> exactly 2 blocks/CU

    const int flat = (int)blockIdx.x;
    const int sp   = flat >> 8;                // parity split 0/1
    const int rb   = flat & 255;
    const int n    = (rb + sp) & (NH - 1);     // head remap (bijective per split)
    const int qt   = rb >> 4;
    const int q0   = qt * BQ;
    const int plen = plen_g[n];

    const int tid  = (int)threadIdx.x;
    const int wave = tid >> 6, lane = tid & 63, quad = lane >> 4, l16 = lane & 15;

    const int ptiles = (plen + 63) >> 6;       // 0..32 prefix tiles (last may be partial)
    const int d0     = q0 >> 6;                // even
    const int tdiag  = d0 + sp;                // the parity-sp diag tile
    const int cnt_p  = (ptiles + 1 - sp) >> 1; // # parity-sp prefix tiles (>=0)
    const int total  = cnt_p + (tdiag >= ptiles ? 1 : 0);   // >= 1 always

    const int qrow  = wave * 16 + l16;
    const int qglob = q0 + qrow;
    const int pmask = (l16 & 7) * 8;           // sP XOR swizzle (bits 3-5; b128-safe)

    const unsigned short* kh = Kb  + (size_t)n * SL * DD;
    const unsigned short* vh = Vtb + (size_t)n * DD * SL;

    // staging lane mapping: each of 8 waves moves one 1KB segment of K and of V per tile
    const int srow = wave * 8 + (lane >> 3);
    const int scol = ((lane & 7) ^ (srow & 7)) * 8;

    auto tile_of = [&](int i) -> int {
        return (i < cnt_p) ? (sp + (i << 1)) : tdiag;
    };
    // stage tile t into buffer b: exactly 2 global_load_lds per wave (K seg + V seg), uniform
    auto stage = [&](int t, int b) {
        const unsigned short* kg = kh + ((size_t)t << 6) * DD;
        const unsigned short* vg = vh + (t << 6);
        gld16(kg + srow * DD + scol, sK[b] + wave * 512);
        gld16(vg + (size_t)srow * SL + scol, sVt[b] + wave * 512);
    };

    // Q fragments first (their consumption wait leaves later stage-loads in flight)
    short8 bQ0, bQ1;
    {
        const float* qf = Qf + ((size_t)(n * QL + qglob)) * DD + quad * 8;
        float4 a0 = *(const float4*)(qf);
        float4 a1 = *(const float4*)(qf + 4);
        float4 c0 = *(const float4*)(qf + 32);
        float4 c1 = *(const float4*)(qf + 36);
        const float S = QK_SCALE_LOG2E;
        unsigned int u0[4] = {
            f2bf2u(a0.x * S, a0.y * S), f2bf2u(a0.z * S, a0.w * S),
            f2bf2u(a1.x * S, a1.y * S), f2bf2u(a1.z * S, a1.w * S) };
        unsigned int u1[4] = {
            f2bf2u(c0.x * S, c0.y * S), f2bf2u(c0.z * S, c0.w * S),
            f2bf2u(c1.x * S, c1.y * S), f2bf2u(c1.z * S, c1.w * S) };
        bQ0 = *(short8*)u0;
        bQ1 = *(short8*)u1;
    }

    // ---- prologue: stage pair 0 (tiles 0 and 1 if present) into buffers 0/1 ----
    stage(tile_of(0), 0);
    if (1 < total) stage(tile_of(1), 1);

    floatx4 acc[4];
    #pragma unroll
    for (int dt = 0; dt < 4; ++dt) acc[dt] = (floatx4){0.f, 0.f, 0.f, 0.f};
    float lsum = 0.f;                          // per-lane partial of l for q = qglob
    unsigned short* pw = sP + qrow * 64;

    // one tile's QK -> softmax -> PV (identical numerics to R3)
    auto do_tile = [&](int t, const unsigned short* sk, const unsigned short* sv) {
        const int s0 = t << 6;

        // ---- S^T = K·Q^T : D[s=st2*16+quad*4+r][q=l16] ----
        floatx4 sf[4];
        #pragma unroll
        for (int st2 = 0; st2 < 4; ++st2) sf[st2] = (floatx4){0.f, 0.f, 0.f, 0.f};
        __builtin_amdgcn_s_setprio(1);
        #pragma unroll
        for (int st2 = 0; st2 < 4; ++st2) {
            int krow = st2 * 16 + l16;
            short8 aK0 = *(const short8*)(sk + krow * 64 + (((0 * 4 + quad) ^ (krow & 7)) * 8));
            short8 aK1 = *(const short8*)(sk + krow * 64 + (((1 * 4 + quad) ^ (krow & 7)) * 8));
            sf[st2] = __builtin_amdgcn_mfma_f32_16x16x32_bf16(aK0, bQ0, sf[st2], 0, 0, 0);
            sf[st2] = __builtin_amdgcn_mfma_f32_16x16x32_bf16(aK1, bQ1, sf[st2], 0, 0, 0);
        }
        __builtin_amdgcn_s_setprio(0);

        // ---- fixed-max softmax: p = exp2(prescaled score); no cross-lane ops ----
        if (s0 + 64 <= plen) {                 // fully-valid tile
            #pragma unroll
            for (int st2 = 0; st2 < 4; ++st2) {
                float p0 = __builtin_amdgcn_exp2f(sf[st2][0]);
                float p1 = __builtin_amdgcn_exp2f(sf[st2][1]);
                float p2 = __builtin_amdgcn_exp2f(sf[st2][2]);
                float p3 = __builtin_amdgcn_exp2f(sf[st2][3]);
                lsum += (p0 + p1) + (p2 + p3);
                uint2 pk = { f2bf2u(p0, p1), f2bf2u(p2, p3) };
                *(uint2*)(pw + ((st2 * 16 + quad * 4) ^ pmask)) = pk;   // P^T-pack, swizzled
            }
        } else {                               // partial/diag tile
            #pragma unroll
            for (int st2 = 0; st2 < 4; ++st2) {
                float p[4];
                #pragma unroll
                for (int r2 = 0; r2 < 4; ++r2) {
                    int s = s0 + st2 * 16 + quad * 4 + r2;
                    bool valid = (s < plen) || (s == qglob);
                    p[r2] = __builtin_amdgcn_exp2f(valid ? sf[st2][r2] : -INFINITY);
                    lsum += p[r2];
                }
                uint2 pk = { f2bf2u(p[0], p[1]), f2bf2u(p[2], p[3]) };
                *(uint2*)(pw + ((st2 * 16 + quad * 4) ^ pmask)) = pk;
            }
        }

        // ---- PV: O[q][d] += P·V (A = P rows q, B = V^T rows d) ----
        __builtin_amdgcn_s_setprio(1);
        #pragma unroll
        for (int ks = 0; ks < 2; ++ks) {
            short8 aP = *(const short8*)(pw + ((ks * 32 + quad * 8) ^ pmask));
            #pragma unroll
            for (int dt = 0; dt < 4; ++dt) {
                int vrow = dt * 16 + l16;
                short8 bV = *(const short8*)(sv + vrow * 64 + (((ks * 4 + quad) ^ (vrow & 7)) * 8));
                acc[dt] = __builtin_amdgcn_mfma_f32_16x16x32_bf16(aP, bV, acc[dt], 0, 0, 0);
            }
        }
        __builtin_amdgcn_s_setprio(0);
    };

    const int np = (total + 1) >> 1;           // tile pairs (last may be single)
    for (int p = 0; p < np; ++p) {
        // pair p staged one full pair-compute ago -> drain is ~free; lgkmcnt(0) closes
        // the ds-read window before anyone overwrites the rotated pair buffers.
        asm volatile("s_waitcnt vmcnt(0) lgkmcnt(0)" ::: "memory");
        __builtin_amdgcn_s_barrier();          // all waves' pair-p loads now landed

        const int i0 = 2 * p;
        const int nb = 2 * ((p + 1) & 1);      // next pair's buffer set
        if (i0 + 2 < total) stage(tile_of(i0 + 2), nb);       // block-uniform conditions
        if (i0 + 3 < total) stage(tile_of(i0 + 3), nb + 1);

        const int cb = 2 * (p & 1);            // this pair's buffer set
        do_tile(tile_of(i0), sK[cb], sVt[cb]);
        if (i0 + 1 < total)
            do_tile(tile_of(i0 + 1), sK[cb + 1], sVt[cb + 1]);
    }

    // ---- epilogue: unnormalized partials, bf16, coalesced via per-wave sP transpose ----
    lsum += __shfl_xor(lsum, 16, 64);
    lsum += __shfl_xor(lsum, 32, 64);
    if (quad == 0)
        Lp[((size_t)sp * NH + n) * QL + q0 + qrow] = lsum;

    unsigned short* pws = sP + wave * 16 * 64;   // wave-private region, free after last PV
    #pragma unroll
    for (int dt = 0; dt < 4; ++dt) {
        int chunk = dt * 2 + (l16 >> 3);
        #pragma unroll
        for (int r2 = 0; r2 < 4; ++r2) {
            int row = quad * 4 + r2;
            int sw = ((chunk ^ (row & 7)) * 8) + (l16 & 7);
            pws[row * 64 + sw] = f2bf(acc[dt][r2]);
        }
    }
    const size_t qbase = ((size_t)sp * NH + n) * QL + q0 + wave * 16;
    #pragma unroll
    for (int t2 = 0; t2 < 2; ++t2) {
        int row = t2 * 8 + (lane >> 3);
        int chunk = lane & 7;
        int sw = (chunk ^ (row & 7)) * 8;
        ushort8v val = *(const ushort8v*)(pws + row * 64 + sw);
        *(ushort8v*)(Opb + (qbase + row) * DD + chunk * 8) = val;
    }
}

// ---------------- combine: O = (Opb[0]+Opb[1]) / (Lp[0]+Lp[1]); branchless (R3 verbatim) ----------------
__global__ __launch_bounds__(512) void k_combine(
    const unsigned short* __restrict__ Opb, const float* __restrict__ Lp,
    float* __restrict__ Og)
{
    const int idx = (int)(blockIdx.x * 512 + threadIdx.x);   // 8-elem group, NH*QL*DD/8 = 262144
    const int d8 = idx & 7;
    const int q  = (idx >> 3) & (QL - 1);
    const int n  = idx >> 14;
    float s[8];
    #pragma unroll
    for (int j = 0; j < 8; ++j) s[j] = 0.f;
    float l = 0.f;
    #pragma unroll
    for (int sp = 0; sp < NSPLIT; ++sp) {      // parity split: both ALWAYS contribute
        const unsigned short* ob = Opb + (((size_t)sp * NH + n) * QL + q) * DD + d8 * 8;
        ushort8v v = *(const ushort8v*)ob;
        #pragma unroll
        for (int j = 0; j < 8; ++j) s[j] += bf2f(v[j]);
        l += Lp[((size_t)sp * NH + n) * QL + q];
    }
    const float inv = 1.0f / l;                // l > 0: diag col always unmasked in one split
    float4 o0 = { s[0] * inv, s[1] * inv, s[2] * inv, s[3] * inv };
    float4 o1 = { s[4] * inv, s[5] * inv, s[6] * inv, s[7] * inv };
    float* og = Og + ((size_t)n * QL + q) * DD + d8 * 8;
    *(float4*)og = o0;
    *(float4*)(og + 4) = o1;
}

extern "C" void kernel_launch(void* const* d_in, const int* in_sizes, int n_in,
                              void* d_out, int out_size, void* d_ws, size_t ws_size,
                              hipStream_t stream) {
    const float* Qf   = (const float*)d_in[0];
    const float* Kf   = (const float*)d_in[1];
    const float* Vf   = (const float*)d_in[2];
    const int*   plen = (const int*)d_in[3];
    float* Og = (float*)d_out;

    char* ws = (char*)d_ws;
    unsigned short* Kb  = (unsigned short*)(ws);                 // 4 MB
    unsigned short* Vtb = (unsigned short*)(ws + (4u << 20));    // 4 MB
    unsigned short* Opb = (unsigned short*)(ws + (8u << 20));    // NSPLIT * 4 MB
    float*          Lp  = (float*)(ws + (16u << 20));            // NSPLIT * 128 KB

    k_prep<<<512, 512, 0, stream>>>(Kf, Vf, Kb, Vtb);
    k_attn<<<NSPLIT * 256, 512, 0, stream>>>(Qf, Kb, Vtb, plen, Opb, Lp);
    k_combine<<<512, 512, 0, stream>>>(Opb, Lp, Og);
}